// Round 1
// baseline (857.154 us; speedup 1.0000x reference)
//
#include <hip/hip_runtime.h>

typedef __bf16 bf16_t;
typedef __bf16 bf16x8 __attribute__((ext_vector_type(8)));
typedef __bf16 bf16x4 __attribute__((ext_vector_type(4)));
typedef float  f32x4  __attribute__((ext_vector_type(4)));

#define SEQ   2048
#define DMODEL 1024
#define DFF   4096
#define NHEAD 16
#define HDIM  64
#define MTOK  8192   // 4 * 2048

// ---------------- workspace layout (bytes) ----------------
#define MB (size_t)(1024*1024)
static const size_t XB_OFF   = 0;          // bf16 [8192][1024]  (aliased by FFN1 later)
static const size_t Q_OFF    = 16*MB;      // bf16 [B,H,S,64]
static const size_t K_OFF    = 32*MB;      // bf16 [B,H,S,64]
static const size_t VT_OFF   = 48*MB;      // bf16 [B,H,64,S]
static const size_t FFN1_OFF = 0;          // bf16 [8192][4096] aliases XB..VT (all dead then)
static const size_t CTX_OFF  = 64*MB;      // bf16 [8192][1024]
static const size_t OUT1_OFF = 80*MB;      // f32  [8192][1024]; later also s2 = out1+out2 (in place)
static const size_t LN1_OFF  = 112*MB;     // bf16 [8192][1024]
static const size_t WQ_OFF   = 128*MB;
static const size_t WK_OFF   = 130*MB;
static const size_t WV_OFF   = 132*MB;
static const size_t WO_OFF   = 134*MB;
static const size_t W1_OFF   = 136*MB;     // bf16 [4096][1024]
static const size_t W2_OFF   = 144*MB;     // bf16 [1024][4096]  (ends at 152MB)

// ---------------- helpers ----------------
__device__ inline void gload16(const void* g, void* l) {
    __builtin_amdgcn_global_load_lds((__attribute__((address_space(1))) void*)g,
                                     (__attribute__((address_space(3))) void*)l, 16, 0, 0);
}

__global__ __launch_bounds__(256) void cast_bf16_k(const float* __restrict__ s,
                                                   bf16_t* __restrict__ d, int n8) {
    int i = blockIdx.x * 256 + threadIdx.x;
    if (i >= n8) return;
    float4 v0 = ((const float4*)s)[2*i];
    float4 v1 = ((const float4*)s)[2*i+1];
    bf16x8 o;
    o[0]=(bf16_t)v0.x; o[1]=(bf16_t)v0.y; o[2]=(bf16_t)v0.z; o[3]=(bf16_t)v0.w;
    o[4]=(bf16_t)v1.x; o[5]=(bf16_t)v1.y; o[6]=(bf16_t)v1.z; o[7]=(bf16_t)v1.w;
    *(bf16x8*)(d + (size_t)i*8) = o;
}

// ---------------- GEMM: C = A(MxK) * B(NxK)^T + bias, epilogue variants ----------------
// EPI 0: Q/K scatter -> bf16 [B,H,S,64]
// EPI 1: V scatter transposed -> bf16 [B,H,64,S]
// EPI 2: fp32 + bias -> out (out1)
// EPI 3: relu -> bf16 (ffn1)
// EPI 4: fp32 + bias + aux[r,c] -> out (s2 = out1+out2, may alias aux)
template<int EPI>
__global__ __launch_bounds__(256, 2) void gemm_bt(
    const bf16_t* __restrict__ A, const bf16_t* __restrict__ Bm,
    const float* __restrict__ bias, void* __restrict__ out,
    const float* __restrict__ aux, int M, int N, int K)
{
    __shared__ bf16_t As[128*64];
    __shared__ bf16_t Bs[128*64];
    const int tid = threadIdx.x;
    const int l   = tid & 63;
    const int wid = tid >> 6;
    const int wm  = wid >> 1, wn = wid & 1;
    const int c16 = l & 15,   g  = l >> 4;
    const long brow = (long)blockIdx.y * 128;
    const long bcol = (long)blockIdx.x * 128;

    f32x4 acc[4][4] = {};

    const int nkt = K >> 6;
    for (int kt = 0; kt < nkt; ++kt) {
        __syncthreads();   // protect LDS while other waves may still be reading
        const bf16_t* Ag = A  + brow * K + kt*64;
        const bf16_t* Bg = Bm + bcol * K + kt*64;
#pragma unroll
        for (int c = 0; c < 4; ++c) {
            int e   = (c*256 + tid) * 8;     // flat bf16 element in 128x64 tile
            int row = e >> 6;
            int col = e & 63;
            gload16(Ag + (long)row*K + col, &As[e]);
            gload16(Bg + (long)row*K + col, &Bs[e]);
        }
        __syncthreads();   // drains vmcnt(0): LDS tiles ready
#pragma unroll
        for (int kk = 0; kk < 2; ++kk) {
            bf16x8 af[4], bfr[4];
#pragma unroll
            for (int mi = 0; mi < 4; ++mi)
                af[mi] = *(const bf16x8*)&As[(wm*64 + mi*16 + c16)*64 + kk*32 + 8*g];
#pragma unroll
            for (int ni = 0; ni < 4; ++ni)
                bfr[ni] = *(const bf16x8*)&Bs[(wn*64 + ni*16 + c16)*64 + kk*32 + 8*g];
#pragma unroll
            for (int mi = 0; mi < 4; ++mi)
#pragma unroll
                for (int ni = 0; ni < 4; ++ni)
                    acc[mi][ni] = __builtin_amdgcn_mfma_f32_16x16x32_bf16(
                        af[mi], bfr[ni], acc[mi][ni], 0, 0, 0);
        }
    }

    // epilogue: lane l, reg i -> row = ...+ g*4 + i, col = ...+ c16
#pragma unroll
    for (int ni = 0; ni < 4; ++ni) {
        const long c = bcol + wn*64 + ni*16 + c16;
        const float bv = bias[c];
#pragma unroll
        for (int mi = 0; mi < 4; ++mi) {
#pragma unroll
            for (int i = 0; i < 4; ++i) {
                const long r = brow + wm*64 + mi*16 + g*4 + i;
                float v = acc[mi][ni][i] + bv;
                if constexpr (EPI == 0) {
                    long off = (((r >> 11)*NHEAD + (c >> 6))*SEQ + (r & (SEQ-1)))*HDIM + (c & 63);
                    ((bf16_t*)out)[off] = (bf16_t)v;
                } else if constexpr (EPI == 1) {
                    long off = (((r >> 11)*NHEAD + (c >> 6))*HDIM + (c & 63))*SEQ + (r & (SEQ-1));
                    ((bf16_t*)out)[off] = (bf16_t)v;
                } else if constexpr (EPI == 2) {
                    ((float*)out)[r*N + c] = v;
                } else if constexpr (EPI == 3) {
                    ((bf16_t*)out)[r*N + c] = (bf16_t)fmaxf(v, 0.f);
                } else {
                    ((float*)out)[r*N + c] = v + aux[r*N + c];
                }
            }
        }
    }
}

// ---------------- flash attention ----------------
// grid: (S/64, B*H). 4 waves/block, each wave owns 16 q-rows; key tiles of 32.
__global__ __launch_bounds__(256, 2) void attn_k(
    const bf16_t* __restrict__ qb, const bf16_t* __restrict__ kb,
    const bf16_t* __restrict__ vt, bf16_t* __restrict__ ctx)
{
    const int bh = blockIdx.y;
    const int w  = threadIdx.x >> 6;
    const int l  = threadIdx.x & 63;
    const int c16 = l & 15, g = l >> 4;
    const int q0 = blockIdx.x*64 + w*16;

    __shared__ bf16_t Ps[4*16*32];
    bf16_t* myP = &Ps[w*512];

    const bf16_t* qrow = qb + ((size_t)bh*SEQ + q0 + c16)*HDIM;
    const bf16x8 aq0 = *(const bf16x8*)(qrow + 8*g);
    const bf16x8 aq1 = *(const bf16x8*)(qrow + 32 + 8*g);

    f32x4 acc[4] = {};
    float m[4]  = {-1e30f, -1e30f, -1e30f, -1e30f};
    float ls[4] = {0.f, 0.f, 0.f, 0.f};

    for (int kt = 0; kt < SEQ/32; ++kt) {
        const bf16_t* kbase = kb + ((size_t)bh*SEQ + kt*32)*HDIM;
        f32x4 z = {0.f,0.f,0.f,0.f};
        bf16x8 b00 = *(const bf16x8*)(kbase + (size_t)c16*HDIM + 8*g);
        bf16x8 b01 = *(const bf16x8*)(kbase + (size_t)c16*HDIM + 32 + 8*g);
        bf16x8 b10 = *(const bf16x8*)(kbase + (size_t)(16+c16)*HDIM + 8*g);
        bf16x8 b11 = *(const bf16x8*)(kbase + (size_t)(16+c16)*HDIM + 32 + 8*g);
        f32x4 s0 = __builtin_amdgcn_mfma_f32_16x16x32_bf16(aq0, b00, z, 0,0,0);
        s0 = __builtin_amdgcn_mfma_f32_16x16x32_bf16(aq1, b01, s0, 0,0,0);
        f32x4 s1 = __builtin_amdgcn_mfma_f32_16x16x32_bf16(aq0, b10, z, 0,0,0);
        s1 = __builtin_amdgcn_mfma_f32_16x16x32_bf16(aq1, b11, s1, 0,0,0);

#pragma unroll
        for (int i = 0; i < 4; ++i) {
            s0[i] *= 0.125f; s1[i] *= 0.125f;
            float pm = fmaxf(s0[i], s1[i]);
#pragma unroll
            for (int msk = 1; msk < 16; msk <<= 1)
                pm = fmaxf(pm, __shfl_xor(pm, msk, 64));
            float mn   = fmaxf(m[i], pm);
            float corr = __expf(m[i] - mn);
            s0[i] = __expf(s0[i] - mn);
            s1[i] = __expf(s1[i] - mn);
            float rsum = s0[i] + s1[i];
#pragma unroll
            for (int msk = 1; msk < 16; msk <<= 1)
                rsum += __shfl_xor(rsum, msk, 64);
            ls[i] = ls[i]*corr + rsum;
            m[i]  = mn;
#pragma unroll
            for (int nf = 0; nf < 4; ++nf) acc[nf][i] *= corr;
        }

#pragma unroll
        for (int i = 0; i < 4; ++i) {
            myP[(g*4+i)*32 + c16]      = (bf16_t)s0[i];
            myP[(g*4+i)*32 + 16 + c16] = (bf16_t)s1[i];
        }
        __syncthreads();
        const bf16x8 ap = *(const bf16x8*)&myP[c16*32 + 8*g];
#pragma unroll
        for (int nf = 0; nf < 4; ++nf) {
            const bf16_t* vrow = vt + ((size_t)bh*HDIM + nf*16 + c16)*SEQ + kt*32 + 8*g;
            bf16x8 bv = *(const bf16x8*)vrow;
            acc[nf] = __builtin_amdgcn_mfma_f32_16x16x32_bf16(ap, bv, acc[nf], 0,0,0);
        }
        __syncthreads();
    }

    const int b = bh >> 4, h = bh & 15;
#pragma unroll
    for (int i = 0; i < 4; ++i) {
        float inv = 1.0f / ls[i];
        long srow = q0 + g*4 + i;
#pragma unroll
        for (int nf = 0; nf < 4; ++nf)
            ctx[((size_t)b*SEQ + srow)*DMODEL + h*HDIM + nf*16 + c16] = (bf16_t)(acc[nf][i]*inv);
    }
}

// ---------------- layer norm: one block per row of 1024 ----------------
__global__ __launch_bounds__(256) void ln_k(
    const float* __restrict__ a, const float* __restrict__ b,
    const float* __restrict__ g, const float* __restrict__ be,
    float* __restrict__ of, bf16_t* __restrict__ ob)
{
    const long row = blockIdx.x;
    const int tid = threadIdx.x;
    float4 v = ((const float4*)(a + row*DMODEL))[tid];
    if (b) {
        float4 u = ((const float4*)(b + row*DMODEL))[tid];
        v.x += u.x; v.y += u.y; v.z += u.z; v.w += u.w;
    }
    float s = v.x + v.y + v.z + v.w;
    float q = v.x*v.x + v.y*v.y + v.z*v.z + v.w*v.w;
#pragma unroll
    for (int msk = 1; msk < 64; msk <<= 1) {
        s += __shfl_xor(s, msk, 64);
        q += __shfl_xor(q, msk, 64);
    }
    __shared__ float sb[4], qb2[4];
    int w = tid >> 6, l = tid & 63;
    if (l == 0) { sb[w] = s; qb2[w] = q; }
    __syncthreads();
    s = sb[0] + sb[1] + sb[2] + sb[3];
    q = qb2[0] + qb2[1] + qb2[2] + qb2[3];
    float mean = s * (1.f/1024.f);
    float var  = q * (1.f/1024.f) - mean*mean;
    float rs   = rsqrtf(var + 1e-5f);
    float4 gv = ((const float4*)g)[tid];
    float4 bv = ((const float4*)be)[tid];
    float o0 = (v.x-mean)*rs*gv.x + bv.x;
    float o1 = (v.y-mean)*rs*gv.y + bv.y;
    float o2 = (v.z-mean)*rs*gv.z + bv.z;
    float o3 = (v.w-mean)*rs*gv.w + bv.w;
    if (ob) {
        bf16x4 o; o[0]=(bf16_t)o0; o[1]=(bf16_t)o1; o[2]=(bf16_t)o2; o[3]=(bf16_t)o3;
        *(bf16x4*)(ob + row*DMODEL + tid*4) = o;
    } else {
        float4 o = make_float4(o0, o1, o2, o3);
        ((float4*)(of + row*DMODEL))[tid] = o;
    }
}

// ---------------- host ----------------
extern "C" void kernel_launch(void* const* d_in, const int* in_sizes, int n_in,
                              void* d_out, int out_size, void* d_ws, size_t ws_size,
                              hipStream_t stream)
{
    const float* x   = (const float*)d_in[0];
    const float* Wq  = (const float*)d_in[1];
    const float* bq  = (const float*)d_in[2];
    const float* Wk  = (const float*)d_in[3];
    const float* bk  = (const float*)d_in[4];
    const float* Wv  = (const float*)d_in[5];
    const float* bvv = (const float*)d_in[6];
    const float* Wo  = (const float*)d_in[7];
    const float* bo  = (const float*)d_in[8];
    const float* W1  = (const float*)d_in[9];
    const float* b1  = (const float*)d_in[10];
    const float* W2  = (const float*)d_in[11];
    const float* b2  = (const float*)d_in[12];
    const float* g1  = (const float*)d_in[13];
    const float* be1 = (const float*)d_in[14];
    const float* g2  = (const float*)d_in[15];
    const float* be2 = (const float*)d_in[16];

    char* ws = (char*)d_ws;
    bf16_t* xb   = (bf16_t*)(ws + XB_OFF);
    bf16_t* qbuf = (bf16_t*)(ws + Q_OFF);
    bf16_t* kbuf = (bf16_t*)(ws + K_OFF);
    bf16_t* vtb  = (bf16_t*)(ws + VT_OFF);
    bf16_t* ffn1 = (bf16_t*)(ws + FFN1_OFF);
    bf16_t* ctxb = (bf16_t*)(ws + CTX_OFF);
    float*  out1 = (float*)(ws + OUT1_OFF);
    bf16_t* ln1b = (bf16_t*)(ws + LN1_OFF);
    bf16_t* wqb  = (bf16_t*)(ws + WQ_OFF);
    bf16_t* wkb  = (bf16_t*)(ws + WK_OFF);
    bf16_t* wvb  = (bf16_t*)(ws + WV_OFF);
    bf16_t* wob  = (bf16_t*)(ws + WO_OFF);
    bf16_t* w1b  = (bf16_t*)(ws + W1_OFF);
    bf16_t* w2b  = (bf16_t*)(ws + W2_OFF);
    float*  dout = (float*)d_out;

    auto cast = [&](const float* s, bf16_t* d, long n) {
        int n8 = (int)(n / 8);
        cast_bf16_k<<<(n8 + 255)/256, 256, 0, stream>>>(s, d, n8);
    };
    cast(x,  xb,  (long)MTOK*DMODEL);
    cast(Wq, wqb, (long)DMODEL*DMODEL);
    cast(Wk, wkb, (long)DMODEL*DMODEL);
    cast(Wv, wvb, (long)DMODEL*DMODEL);
    cast(Wo, wob, (long)DMODEL*DMODEL);
    cast(W1, w1b, (long)DFF*DMODEL);
    cast(W2, w2b, (long)DMODEL*DFF);

    dim3 blk(256);
    // QKV projections
    gemm_bt<0><<<dim3(DMODEL/128, MTOK/128), blk, 0, stream>>>(xb, wqb, bq, qbuf, nullptr, MTOK, DMODEL, DMODEL);
    gemm_bt<0><<<dim3(DMODEL/128, MTOK/128), blk, 0, stream>>>(xb, wkb, bk, kbuf, nullptr, MTOK, DMODEL, DMODEL);
    gemm_bt<1><<<dim3(DMODEL/128, MTOK/128), blk, 0, stream>>>(xb, wvb, bvv, vtb, nullptr, MTOK, DMODEL, DMODEL);
    // attention
    attn_k<<<dim3(SEQ/64, 4*NHEAD), blk, 0, stream>>>(qbuf, kbuf, vtb, ctxb);
    // Wo projection -> out1 (fp32)
    gemm_bt<2><<<dim3(DMODEL/128, MTOK/128), blk, 0, stream>>>(ctxb, wob, bo, out1, nullptr, MTOK, DMODEL, DMODEL);
    // LN1: ln1 = LN(x + out1) -> bf16
    ln_k<<<MTOK, blk, 0, stream>>>(x, out1, g1, be1, nullptr, ln1b);
    // FFN1: relu(ln1 @ W1^T + b1) -> bf16
    gemm_bt<3><<<dim3(DFF/128, MTOK/128), blk, 0, stream>>>(ln1b, w1b, b1, ffn1, nullptr, MTOK, DFF, DMODEL);
    // FFN2: s2 = out1 + (ffn1 @ W2^T + b2) -> fp32, in place over out1
    gemm_bt<4><<<dim3(DMODEL/128, MTOK/128), blk, 0, stream>>>(ffn1, w2b, b2, out1, out1, MTOK, DMODEL, DFF);
    // LN2 -> d_out (fp32)
    ln_k<<<MTOK, blk, 0, stream>>>(out1, nullptr, g2, be2, dout, nullptr);
}

// Round 2
// 799.625 us; speedup vs baseline: 1.0719x; 1.0719x over previous
//
#include <hip/hip_runtime.h>

typedef __bf16 bf16_t;
typedef __bf16 bf16x8 __attribute__((ext_vector_type(8)));
typedef __bf16 bf16x4 __attribute__((ext_vector_type(4)));
typedef float  f32x4  __attribute__((ext_vector_type(4)));

#define SEQ   2048
#define DMODEL 1024
#define DFF   4096
#define NHEAD 16
#define HDIM  64
#define MTOK  8192   // 4 * 2048

// ---------------- workspace layout (bytes) ----------------
#define MB (size_t)(1024*1024)
static const size_t XB_OFF   = 0;          // bf16 [8192][1024]  (aliased by FFN1 later)
static const size_t Q_OFF    = 16*MB;      // bf16 [B,H,S,64]
static const size_t K_OFF    = 32*MB;      // bf16 [B,H,S,64]
static const size_t VT_OFF   = 48*MB;      // bf16 [B,H,64,S]
static const size_t FFN1_OFF = 0;          // bf16 [8192][4096] aliases XB..VT (all dead then)
static const size_t CTX_OFF  = 64*MB;      // bf16 [8192][1024]
static const size_t OUT1_OFF = 80*MB;      // f32  [8192][1024]; later s2 = out1+out2 in place
static const size_t LN1_OFF  = 112*MB;     // bf16 [8192][1024]
static const size_t WQ_OFF   = 128*MB;
static const size_t WK_OFF   = 130*MB;
static const size_t WV_OFF   = 132*MB;
static const size_t WO_OFF   = 134*MB;
static const size_t W1_OFF   = 136*MB;     // bf16 [4096][1024]
static const size_t W2_OFF   = 144*MB;     // bf16 [1024][4096]  (ends at 152MB)

// ---------------- helpers ----------------
__device__ inline void gload16(const void* g, void* l) {
    __builtin_amdgcn_global_load_lds((__attribute__((address_space(1))) void*)g,
                                     (__attribute__((address_space(3))) void*)l, 16, 0, 0);
}

__global__ __launch_bounds__(256) void cast_bf16_k(const float* __restrict__ s,
                                                   bf16_t* __restrict__ d, int n8) {
    int i = blockIdx.x * 256 + threadIdx.x;
    if (i >= n8) return;
    float4 v0 = ((const float4*)s)[2*i];
    float4 v1 = ((const float4*)s)[2*i+1];
    bf16x8 o;
    o[0]=(bf16_t)v0.x; o[1]=(bf16_t)v0.y; o[2]=(bf16_t)v0.z; o[3]=(bf16_t)v0.w;
    o[4]=(bf16_t)v1.x; o[5]=(bf16_t)v1.y; o[6]=(bf16_t)v1.z; o[7]=(bf16_t)v1.w;
    *(bf16x8*)(d + (size_t)i*8) = o;
}

// ---------------- GEMM: C = (A(MxK) * B(NxK)^T + bias) * scale, epilogue variants ----------------
// EPI 0: Q/K scatter -> bf16 [B,H,S,64]   (scale folds the 1/sqrt(hd) into Q)
// EPI 1: V scatter transposed -> bf16 [B,H,64,S]
// EPI 2: fp32 + bias -> out (out1)
// EPI 3: relu -> bf16 (ffn1)
// EPI 4: fp32 + bias + aux[r,c] -> out (s2 = out1+out2, may alias aux)
template<int EPI>
__global__ __launch_bounds__(256, 2) void gemm_bt(
    const bf16_t* __restrict__ A, const bf16_t* __restrict__ Bm,
    const float* __restrict__ bias, void* __restrict__ out,
    const float* __restrict__ aux, int M, int N, int K, float scale)
{
    __shared__ bf16_t As[128*64];
    __shared__ bf16_t Bs[128*64];
    const int tid = threadIdx.x;
    const int l   = tid & 63;
    const int wid = tid >> 6;
    const int wm  = wid >> 1, wn = wid & 1;
    const int c16 = l & 15,   g  = l >> 4;
    const long brow = (long)blockIdx.y * 128;
    const long bcol = (long)blockIdx.x * 128;

    f32x4 acc[4][4] = {};

    const int nkt = K >> 6;
    for (int kt = 0; kt < nkt; ++kt) {
        __syncthreads();   // protect LDS while other waves may still be reading
        const bf16_t* Ag = A  + brow * K + kt*64;
        const bf16_t* Bg = Bm + bcol * K + kt*64;
#pragma unroll
        for (int c = 0; c < 4; ++c) {
            int e   = (c*256 + tid) * 8;     // flat bf16 element in 128x64 tile
            int row = e >> 6;
            int col = e & 63;
            gload16(Ag + (long)row*K + col, &As[e]);
            gload16(Bg + (long)row*K + col, &Bs[e]);
        }
        __syncthreads();   // drains vmcnt(0): LDS tiles ready
#pragma unroll
        for (int kk = 0; kk < 2; ++kk) {
            bf16x8 af[4], bfr[4];
#pragma unroll
            for (int mi = 0; mi < 4; ++mi)
                af[mi] = *(const bf16x8*)&As[(wm*64 + mi*16 + c16)*64 + kk*32 + 8*g];
#pragma unroll
            for (int ni = 0; ni < 4; ++ni)
                bfr[ni] = *(const bf16x8*)&Bs[(wn*64 + ni*16 + c16)*64 + kk*32 + 8*g];
#pragma unroll
            for (int mi = 0; mi < 4; ++mi)
#pragma unroll
                for (int ni = 0; ni < 4; ++ni)
                    acc[mi][ni] = __builtin_amdgcn_mfma_f32_16x16x32_bf16(
                        af[mi], bfr[ni], acc[mi][ni], 0, 0, 0);
        }
    }

    // epilogue: lane l, reg i -> row = ...+ g*4 + i, col = ...+ c16
#pragma unroll
    for (int ni = 0; ni < 4; ++ni) {
        const long c = bcol + wn*64 + ni*16 + c16;
        const float bv = bias[c];
#pragma unroll
        for (int mi = 0; mi < 4; ++mi) {
#pragma unroll
            for (int i = 0; i < 4; ++i) {
                const long r = brow + wm*64 + mi*16 + g*4 + i;
                float v = (acc[mi][ni][i] + bv) * scale;
                if constexpr (EPI == 0) {
                    long off = (((r >> 11)*NHEAD + (c >> 6))*SEQ + (r & (SEQ-1)))*HDIM + (c & 63);
                    ((bf16_t*)out)[off] = (bf16_t)v;
                } else if constexpr (EPI == 1) {
                    long off = (((r >> 11)*NHEAD + (c >> 6))*HDIM + (c & 63))*SEQ + (r & (SEQ-1));
                    ((bf16_t*)out)[off] = (bf16_t)v;
                } else if constexpr (EPI == 2) {
                    ((float*)out)[r*N + c] = v;
                } else if constexpr (EPI == 3) {
                    ((bf16_t*)out)[r*N + c] = (bf16_t)fmaxf(v, 0.f);
                } else {
                    ((float*)out)[r*N + c] = v + aux[r*N + c];
                }
            }
        }
    }
}

// ---------------- flash attention, barrier-free ----------------
// grid: (S/64, B*H). 4 independent waves/block, each wave owns 16 q-rows.
// KVBLK = 64 keys/iteration. Key permutation: QK B-frag j covers key 4*c16+j,
// so each lane holds 4 ADJACENT keys per q-row -> single ds_write_b64 per row
// into an XOR-swizzled [16 rows][128B] P tile; PV A-frag ds_read_b128 with the
// same swizzle tiles all 32 banks (conflict-free).
__global__ __launch_bounds__(256, 3) void attn_k(
    const bf16_t* __restrict__ qb, const bf16_t* __restrict__ kb,
    const bf16_t* __restrict__ vt, bf16_t* __restrict__ ctx)
{
    const int bh = blockIdx.y;
    const int w  = threadIdx.x >> 6;
    const int l  = threadIdx.x & 63;
    const int c16 = l & 15, g = l >> 4;
    const int q0 = blockIdx.x*64 + w*16;

    __shared__ char Ps[4*2048];
    char* myP = &Ps[w*2048];

    // Q fragment: A[row=c16][k=8g..8g+7] per 32-wide k-step (Q pre-scaled by 1/8)
    const bf16_t* qrow = qb + ((size_t)bh*SEQ + q0 + c16)*HDIM;
    const bf16x8 aq0 = *(const bf16x8*)(qrow + 8*g);
    const bf16x8 aq1 = *(const bf16x8*)(qrow + 32 + 8*g);

    const bf16_t* kb0 = kb + (size_t)bh*SEQ*HDIM;
    const bf16_t* vt0 = vt + (size_t)bh*HDIM*SEQ;

    f32x4 acc[4] = {};
    float m[4]  = {-1e30f, -1e30f, -1e30f, -1e30f};
    float ls[4] = {0.f, 0.f, 0.f, 0.f};

    for (int kt = 0; kt < SEQ/64; ++kt) {
        const bf16_t* kbase = kb0 + (size_t)kt*64*HDIM;
        // ---- QK^T: s[j][i] = S[q = 4g+i][key = 4*c16 + j] ----
        f32x4 s[4];
#pragma unroll
        for (int j = 0; j < 4; ++j) {
            const bf16_t* krow = kbase + (size_t)(4*c16 + j)*HDIM;
            bf16x8 k0 = *(const bf16x8*)(krow + 8*g);
            bf16x8 k1 = *(const bf16x8*)(krow + 32 + 8*g);
            f32x4 z = {0.f, 0.f, 0.f, 0.f};
            s[j] = __builtin_amdgcn_mfma_f32_16x16x32_bf16(aq0, k0, z, 0, 0, 0);
            s[j] = __builtin_amdgcn_mfma_f32_16x16x32_bf16(aq1, k1, s[j], 0, 0, 0);
        }
        // ---- online softmax: q fixed by (g,i); keys spread over (c16, j) ----
#pragma unroll
        for (int i = 0; i < 4; ++i) {
            float pm = fmaxf(fmaxf(s[0][i], s[1][i]), fmaxf(s[2][i], s[3][i]));
#pragma unroll
            for (int msk = 1; msk < 16; msk <<= 1)
                pm = fmaxf(pm, __shfl_xor(pm, msk, 64));
            float mn   = fmaxf(m[i], pm);
            float corr = __expf(m[i] - mn);
            float rsum = 0.f;
#pragma unroll
            for (int j = 0; j < 4; ++j) { s[j][i] = __expf(s[j][i] - mn); rsum += s[j][i]; }
#pragma unroll
            for (int msk = 1; msk < 16; msk <<= 1)
                rsum += __shfl_xor(rsum, msk, 64);
            ls[i] = ls[i]*corr + rsum;
            m[i]  = mn;
#pragma unroll
            for (int nf = 0; nf < 4; ++nf) acc[nf][i] *= corr;
        }
        // ---- P -> LDS: row = 4g+i, bf16 cols 4*c16..4*c16+3, swizzled ----
#pragma unroll
        for (int i = 0; i < 4; ++i) {
            const int row = 4*g + i;
            bf16x4 pk;
            pk[0]=(bf16_t)s[0][i]; pk[1]=(bf16_t)s[1][i];
            pk[2]=(bf16_t)s[2][i]; pk[3]=(bf16_t)s[3][i];
            *(bf16x4*)(myP + row*128 + ((8*c16) ^ ((row & 7) << 4))) = pk;
        }
        asm volatile("s_waitcnt lgkmcnt(0)" ::: "memory");  // writes visible wave-wide
        // ---- PV: A = P[row=c16][keys ks*32+8g..+7], B = V^T rows d=16nf+c16 ----
#pragma unroll
        for (int ks = 0; ks < 2; ++ks) {
            bf16x8 pa = *(const bf16x8*)(myP + c16*128 + ((ks*64 + 16*g) ^ ((c16 & 7) << 4)));
#pragma unroll
            for (int nf = 0; nf < 4; ++nf) {
                bf16x8 bv = *(const bf16x8*)(vt0 + (size_t)(nf*16 + c16)*SEQ + kt*64 + ks*32 + 8*g);
                acc[nf] = __builtin_amdgcn_mfma_f32_16x16x32_bf16(pa, bv, acc[nf], 0, 0, 0);
            }
        }
        asm volatile("" ::: "memory");  // pin reads before next iteration's P writes
    }

    const int b = bh >> 4, h = bh & 15;
#pragma unroll
    for (int i = 0; i < 4; ++i) {
        float inv = 1.0f / ls[i];
        long srow = q0 + g*4 + i;
#pragma unroll
        for (int nf = 0; nf < 4; ++nf)
            ctx[((size_t)b*SEQ + srow)*DMODEL + h*HDIM + nf*16 + c16] = (bf16_t)(acc[nf][i]*inv);
    }
}

// ---------------- layer norm: one block per row of 1024 ----------------
__global__ __launch_bounds__(256) void ln_k(
    const float* __restrict__ a, const float* __restrict__ b,
    const float* __restrict__ g, const float* __restrict__ be,
    float* __restrict__ of, bf16_t* __restrict__ ob)
{
    const long row = blockIdx.x;
    const int tid = threadIdx.x;
    float4 v = ((const float4*)(a + row*DMODEL))[tid];
    if (b) {
        float4 u = ((const float4*)(b + row*DMODEL))[tid];
        v.x += u.x; v.y += u.y; v.z += u.z; v.w += u.w;
    }
    float s = v.x + v.y + v.z + v.w;
    float q = v.x*v.x + v.y*v.y + v.z*v.z + v.w*v.w;
#pragma unroll
    for (int msk = 1; msk < 64; msk <<= 1) {
        s += __shfl_xor(s, msk, 64);
        q += __shfl_xor(q, msk, 64);
    }
    __shared__ float sb[4], qb2[4];
    int w = tid >> 6, lid = tid & 63;
    if (lid == 0) { sb[w] = s; qb2[w] = q; }
    __syncthreads();
    s = sb[0] + sb[1] + sb[2] + sb[3];
    q = qb2[0] + qb2[1] + qb2[2] + qb2[3];
    float mean = s * (1.f/1024.f);
    float var  = q * (1.f/1024.f) - mean*mean;
    float rs   = rsqrtf(var + 1e-5f);
    float4 gv = ((const float4*)g)[tid];
    float4 bv = ((const float4*)be)[tid];
    float o0 = (v.x-mean)*rs*gv.x + bv.x;
    float o1 = (v.y-mean)*rs*gv.y + bv.y;
    float o2 = (v.z-mean)*rs*gv.z + bv.z;
    float o3 = (v.w-mean)*rs*gv.w + bv.w;
    if (ob) {
        bf16x4 o; o[0]=(bf16_t)o0; o[1]=(bf16_t)o1; o[2]=(bf16_t)o2; o[3]=(bf16_t)o3;
        *(bf16x4*)(ob + row*DMODEL + tid*4) = o;
    } else {
        float4 o = make_float4(o0, o1, o2, o3);
        ((float4*)(of + row*DMODEL))[tid] = o;
    }
}

// ---------------- host ----------------
extern "C" void kernel_launch(void* const* d_in, const int* in_sizes, int n_in,
                              void* d_out, int out_size, void* d_ws, size_t ws_size,
                              hipStream_t stream)
{
    const float* x   = (const float*)d_in[0];
    const float* Wq  = (const float*)d_in[1];
    const float* bq  = (const float*)d_in[2];
    const float* Wk  = (const float*)d_in[3];
    const float* bk  = (const float*)d_in[4];
    const float* Wv  = (const float*)d_in[5];
    const float* bvv = (const float*)d_in[6];
    const float* Wo  = (const float*)d_in[7];
    const float* bo  = (const float*)d_in[8];
    const float* W1  = (const float*)d_in[9];
    const float* b1  = (const float*)d_in[10];
    const float* W2  = (const float*)d_in[11];
    const float* b2  = (const float*)d_in[12];
    const float* g1  = (const float*)d_in[13];
    const float* be1 = (const float*)d_in[14];
    const float* g2  = (const float*)d_in[15];
    const float* be2 = (const float*)d_in[16];

    char* ws = (char*)d_ws;
    bf16_t* xb   = (bf16_t*)(ws + XB_OFF);
    bf16_t* qbuf = (bf16_t*)(ws + Q_OFF);
    bf16_t* kbuf = (bf16_t*)(ws + K_OFF);
    bf16_t* vtb  = (bf16_t*)(ws + VT_OFF);
    bf16_t* ffn1 = (bf16_t*)(ws + FFN1_OFF);
    bf16_t* ctxb = (bf16_t*)(ws + CTX_OFF);
    float*  out1 = (float*)(ws + OUT1_OFF);
    bf16_t* ln1b = (bf16_t*)(ws + LN1_OFF);
    bf16_t* wqb  = (bf16_t*)(ws + WQ_OFF);
    bf16_t* wkb  = (bf16_t*)(ws + WK_OFF);
    bf16_t* wvb  = (bf16_t*)(ws + WV_OFF);
    bf16_t* wob  = (bf16_t*)(ws + WO_OFF);
    bf16_t* w1b  = (bf16_t*)(ws + W1_OFF);
    bf16_t* w2b  = (bf16_t*)(ws + W2_OFF);
    float*  dout = (float*)d_out;

    auto cast = [&](const float* s, bf16_t* d, long n) {
        int n8 = (int)(n / 8);
        cast_bf16_k<<<(n8 + 255)/256, 256, 0, stream>>>(s, d, n8);
    };
    cast(x,  xb,  (long)MTOK*DMODEL);
    cast(Wq, wqb, (long)DMODEL*DMODEL);
    cast(Wk, wkb, (long)DMODEL*DMODEL);
    cast(Wv, wvb, (long)DMODEL*DMODEL);
    cast(Wo, wob, (long)DMODEL*DMODEL);
    cast(W1, w1b, (long)DFF*DMODEL);
    cast(W2, w2b, (long)DMODEL*DFF);

    dim3 blk(256);
    // QKV projections (Q pre-scaled by 1/sqrt(hd) = 0.125)
    gemm_bt<0><<<dim3(DMODEL/128, MTOK/128), blk, 0, stream>>>(xb, wqb, bq, qbuf, nullptr, MTOK, DMODEL, DMODEL, 0.125f);
    gemm_bt<0><<<dim3(DMODEL/128, MTOK/128), blk, 0, stream>>>(xb, wkb, bk, kbuf, nullptr, MTOK, DMODEL, DMODEL, 1.f);
    gemm_bt<1><<<dim3(DMODEL/128, MTOK/128), blk, 0, stream>>>(xb, wvb, bvv, vtb, nullptr, MTOK, DMODEL, DMODEL, 1.f);
    // attention
    attn_k<<<dim3(SEQ/64, 4*NHEAD), blk, 0, stream>>>(qbuf, kbuf, vtb, ctxb);
    // Wo projection -> out1 (fp32)
    gemm_bt<2><<<dim3(DMODEL/128, MTOK/128), blk, 0, stream>>>(ctxb, wob, bo, out1, nullptr, MTOK, DMODEL, DMODEL, 1.f);
    // LN1: ln1 = LN(x + out1) -> bf16
    ln_k<<<MTOK, blk, 0, stream>>>(x, out1, g1, be1, nullptr, ln1b);
    // FFN1: relu(ln1 @ W1^T + b1) -> bf16
    gemm_bt<3><<<dim3(DFF/128, MTOK/128), blk, 0, stream>>>(ln1b, w1b, b1, ffn1, nullptr, MTOK, DFF, DMODEL, 1.f);
    // FFN2: s2 = out1 + (ffn1 @ W2^T + b2) -> fp32, in place over out1
    gemm_bt<4><<<dim3(DMODEL/128, MTOK/128), blk, 0, stream>>>(ffn1, w2b, b2, out1, out1, MTOK, DMODEL, DFF, 1.f);
    // LN2 -> d_out (fp32)
    ln_k<<<MTOK, blk, 0, stream>>>(out1, nullptr, g2, be2, dout, nullptr);
}

// Round 3
// 587.389 us; speedup vs baseline: 1.4593x; 1.3613x over previous
//
#include <hip/hip_runtime.h>

typedef __bf16 bf16_t;
typedef __bf16 bf16x8 __attribute__((ext_vector_type(8)));
typedef __bf16 bf16x4 __attribute__((ext_vector_type(4)));
typedef float  f32x4  __attribute__((ext_vector_type(4)));

#define SEQ   2048
#define DMODEL 1024
#define DFF   4096
#define NHEAD 16
#define HDIM  64
#define MTOK  8192   // 4 * 2048

// ---------------- workspace layout (bytes) ----------------
#define MB (size_t)(1024*1024)
static const size_t XB_OFF   = 0;          // bf16 [8192][1024]  (aliased by FFN1 later)
static const size_t Q_OFF    = 16*MB;      // bf16 [B,H,S,64]
static const size_t K_OFF    = 32*MB;      // bf16 [B,H,S,64]
static const size_t VT_OFF   = 48*MB;      // bf16 [B,H,64,S]
static const size_t FFN1_OFF = 0;          // bf16 [8192][4096] aliases XB..VT (all dead then)
static const size_t CTX_OFF  = 64*MB;      // bf16 [8192][1024]
static const size_t OUT1_OFF = 80*MB;      // f32  [8192][1024]; later s2 = out1+out2 in place
static const size_t LN1_OFF  = 112*MB;     // bf16 [8192][1024]
static const size_t WQ_OFF   = 128*MB;
static const size_t WK_OFF   = 130*MB;
static const size_t WV_OFF   = 132*MB;
static const size_t WO_OFF   = 134*MB;
static const size_t W1_OFF   = 136*MB;     // bf16 [4096][1024]
static const size_t W2_OFF   = 144*MB;     // bf16 [1024][4096]  (ends at 152MB)

// ---------------- helpers ----------------
__device__ inline void gload16(const void* g, void* l) {
    __builtin_amdgcn_global_load_lds((__attribute__((address_space(1))) void*)g,
                                     (__attribute__((address_space(3))) void*)l, 16, 0, 0);
}

__global__ __launch_bounds__(256) void cast_bf16_k(const float* __restrict__ s,
                                                   bf16_t* __restrict__ d, int n8) {
    int i = blockIdx.x * 256 + threadIdx.x;
    if (i >= n8) return;
    float4 v0 = ((const float4*)s)[2*i];
    float4 v1 = ((const float4*)s)[2*i+1];
    bf16x8 o;
    o[0]=(bf16_t)v0.x; o[1]=(bf16_t)v0.y; o[2]=(bf16_t)v0.z; o[3]=(bf16_t)v0.w;
    o[4]=(bf16_t)v1.x; o[5]=(bf16_t)v1.y; o[6]=(bf16_t)v1.z; o[7]=(bf16_t)v1.w;
    *(bf16x8*)(d + (size_t)i*8) = o;
}

// ---------------- GEMM: C = (A(MxK) * B(NxK)^T + bias) * scale, epilogue variants ----------------
// EPI 0: Q/K scatter -> bf16 [B,H,S,64]   (scale folds the 1/sqrt(hd) into Q)
// EPI 1: V scatter transposed -> bf16 [B,H,64,S]
// EPI 2: fp32 + bias -> out (out1)
// EPI 3: relu -> bf16 (ffn1)
// EPI 4: fp32 + bias + aux[r,c] -> out (s2 = out1+out2, may alias aux)
template<int EPI>
__global__ __launch_bounds__(256, 2) void gemm_bt(
    const bf16_t* __restrict__ A, const bf16_t* __restrict__ Bm,
    const float* __restrict__ bias, void* __restrict__ out,
    const float* __restrict__ aux, int M, int N, int K, float scale)
{
    __shared__ bf16_t As[128*64];
    __shared__ bf16_t Bs[128*64];
    const int tid = threadIdx.x;
    const int l   = tid & 63;
    const int wid = tid >> 6;
    const int wm  = wid >> 1, wn = wid & 1;
    const int c16 = l & 15,   g  = l >> 4;
    const long brow = (long)blockIdx.y * 128;
    const long bcol = (long)blockIdx.x * 128;

    f32x4 acc[4][4] = {};

    const int nkt = K >> 6;
    for (int kt = 0; kt < nkt; ++kt) {
        __syncthreads();   // protect LDS while other waves may still be reading
        const bf16_t* Ag = A  + brow * K + kt*64;
        const bf16_t* Bg = Bm + bcol * K + kt*64;
#pragma unroll
        for (int c = 0; c < 4; ++c) {
            int e   = (c*256 + tid) * 8;     // flat bf16 element in 128x64 tile
            int row = e >> 6;
            int col = e & 63;
            gload16(Ag + (long)row*K + col, &As[e]);
            gload16(Bg + (long)row*K + col, &Bs[e]);
        }
        __syncthreads();   // drains vmcnt(0): LDS tiles ready
#pragma unroll
        for (int kk = 0; kk < 2; ++kk) {
            bf16x8 af[4], bfr[4];
#pragma unroll
            for (int mi = 0; mi < 4; ++mi)
                af[mi] = *(const bf16x8*)&As[(wm*64 + mi*16 + c16)*64 + kk*32 + 8*g];
#pragma unroll
            for (int ni = 0; ni < 4; ++ni)
                bfr[ni] = *(const bf16x8*)&Bs[(wn*64 + ni*16 + c16)*64 + kk*32 + 8*g];
#pragma unroll
            for (int mi = 0; mi < 4; ++mi)
#pragma unroll
                for (int ni = 0; ni < 4; ++ni)
                    acc[mi][ni] = __builtin_amdgcn_mfma_f32_16x16x32_bf16(
                        af[mi], bfr[ni], acc[mi][ni], 0, 0, 0);
        }
    }

    // epilogue: lane l, reg i -> row = ...+ g*4 + i, col = ...+ c16
#pragma unroll
    for (int ni = 0; ni < 4; ++ni) {
        const long c = bcol + wn*64 + ni*16 + c16;
        const float bv = bias[c];
#pragma unroll
        for (int mi = 0; mi < 4; ++mi) {
#pragma unroll
            for (int i = 0; i < 4; ++i) {
                const long r = brow + wm*64 + mi*16 + g*4 + i;
                float v = (acc[mi][ni][i] + bv) * scale;
                if constexpr (EPI == 0) {
                    long off = (((r >> 11)*NHEAD + (c >> 6))*SEQ + (r & (SEQ-1)))*HDIM + (c & 63);
                    ((bf16_t*)out)[off] = (bf16_t)v;
                } else if constexpr (EPI == 1) {
                    long off = (((r >> 11)*NHEAD + (c >> 6))*HDIM + (c & 63))*SEQ + (r & (SEQ-1));
                    ((bf16_t*)out)[off] = (bf16_t)v;
                } else if constexpr (EPI == 2) {
                    ((float*)out)[r*N + c] = v;
                } else if constexpr (EPI == 3) {
                    ((bf16_t*)out)[r*N + c] = (bf16_t)fmaxf(v, 0.f);
                } else {
                    ((float*)out)[r*N + c] = v + aux[r*N + c];
                }
            }
        }
    }
}

// ---------------- flash attention, register-pipelined ----------------
// grid: (S/128, B*H). 4 independent waves/block, each wave owns 32 q-rows
// (two 16-row MFMA fragments). KVBLK = 64 keys/iteration. K is double-buffered
// in registers (kt+1 issued at top of kt); V is issued at top, consumed at the
// end (QK+softmax hides its latency). P goes through a parity-double-buffered
// XOR-swizzled LDS tile (verified conflict-free in round 2).
__device__ __forceinline__ void kload(bf16x8 (&dst)[4][2], const bf16_t* kb0,
                                      int ktt, int c16, int g) {
    const bf16_t* kbase = kb0 + (size_t)ktt*64*HDIM;
#pragma unroll
    for (int j = 0; j < 4; ++j)
#pragma unroll
        for (int ks = 0; ks < 2; ++ks)
            dst[j][ks] = *(const bf16x8*)(kbase + (size_t)(4*c16 + j)*HDIM + ks*32 + 8*g);
}

__device__ __forceinline__ void vload(bf16x8 (&vr)[4][2], const bf16_t* vt0,
                                      int ktt, int c16, int g) {
#pragma unroll
    for (int nf = 0; nf < 4; ++nf)
#pragma unroll
        for (int ks = 0; ks < 2; ++ks)
            vr[nf][ks] = *(const bf16x8*)(vt0 + (size_t)(16*nf + c16)*SEQ + ktt*64 + ks*32 + 8*g);
}

__device__ __forceinline__ void attn_step(
    const bf16x8 (&kr)[4][2], const bf16x8 (&vr)[4][2], const bf16x8 (&aq)[2][2],
    f32x4 (&acc)[2][4], float (&m)[2][4], float (&ls)[2][4],
    char* myP, int c16, int g)
{
    f32x4 s[2][4];
    const f32x4 z = {0.f, 0.f, 0.f, 0.f};
#pragma unroll
    for (int f = 0; f < 2; ++f)
#pragma unroll
        for (int j = 0; j < 4; ++j) {
            s[f][j] = __builtin_amdgcn_mfma_f32_16x16x32_bf16(aq[f][0], kr[j][0], z, 0, 0, 0);
            s[f][j] = __builtin_amdgcn_mfma_f32_16x16x32_bf16(aq[f][1], kr[j][1], s[f][j], 0, 0, 0);
        }
#pragma unroll
    for (int f = 0; f < 2; ++f)
#pragma unroll
        for (int i = 0; i < 4; ++i) {
            float pm = fmaxf(fmaxf(s[f][0][i], s[f][1][i]), fmaxf(s[f][2][i], s[f][3][i]));
#pragma unroll
            for (int msk = 1; msk < 16; msk <<= 1)
                pm = fmaxf(pm, __shfl_xor(pm, msk, 64));
            float mn   = fmaxf(m[f][i], pm);
            float corr = __expf(m[f][i] - mn);
            float rsum = 0.f;
#pragma unroll
            for (int j = 0; j < 4; ++j) { s[f][j][i] = __expf(s[f][j][i] - mn); rsum += s[f][j][i]; }
#pragma unroll
            for (int msk = 1; msk < 16; msk <<= 1)
                rsum += __shfl_xor(rsum, msk, 64);
            ls[f][i] = ls[f][i]*corr + rsum;
            m[f][i]  = mn;
#pragma unroll
            for (int nf = 0; nf < 4; ++nf) acc[f][nf][i] *= corr;
        }
    // P -> LDS: row = f*16 + 4g + i (q), bf16 cols 4*c16..4*c16+3 (keys), swizzled
#pragma unroll
    for (int f = 0; f < 2; ++f)
#pragma unroll
        for (int i = 0; i < 4; ++i) {
            const int rw = f*16 + 4*g + i;
            bf16x4 pk;
            pk[0]=(bf16_t)s[f][0][i]; pk[1]=(bf16_t)s[f][1][i];
            pk[2]=(bf16_t)s[f][2][i]; pk[3]=(bf16_t)s[f][3][i];
            *(bf16x4*)(myP + rw*128 + ((8*c16) ^ ((rw & 7) << 4))) = pk;
        }
    asm volatile("s_waitcnt lgkmcnt(0)" ::: "memory");  // P writes visible (lgkm only; vm loads stay in flight)
    __builtin_amdgcn_sched_barrier(0);
    // PV: A = P[row = f*16+c16][keys ks*32+8g..], B = V^T rows d = 16nf+c16
#pragma unroll
    for (int f = 0; f < 2; ++f)
#pragma unroll
        for (int ks = 0; ks < 2; ++ks) {
            bf16x8 pa = *(const bf16x8*)(myP + (f*16 + c16)*128 + ((ks*64 + 16*g) ^ ((c16 & 7) << 4)));
#pragma unroll
            for (int nf = 0; nf < 4; ++nf)
                acc[f][nf] = __builtin_amdgcn_mfma_f32_16x16x32_bf16(pa, vr[nf][ks], acc[f][nf], 0, 0, 0);
        }
}

__global__ __launch_bounds__(256, 2) void attn_k(
    const bf16_t* __restrict__ qb, const bf16_t* __restrict__ kb,
    const bf16_t* __restrict__ vt, bf16_t* __restrict__ ctx)
{
    const int bh = blockIdx.y;
    const int w  = threadIdx.x >> 6;
    const int l  = threadIdx.x & 63;
    const int c16 = l & 15, g = l >> 4;
    const int q0 = blockIdx.x*128 + w*32;

    __shared__ char Ps[4*8192];
    char* myP = &Ps[w*8192];

    // Q fragments: A[row=c16][k=8g..8g+7] per 32-wide k-step (Q pre-scaled by 1/8)
    bf16x8 aq[2][2];
#pragma unroll
    for (int f = 0; f < 2; ++f) {
        const bf16_t* qrow = qb + ((size_t)bh*SEQ + q0 + f*16 + c16)*HDIM;
        aq[f][0] = *(const bf16x8*)(qrow + 8*g);
        aq[f][1] = *(const bf16x8*)(qrow + 32 + 8*g);
    }

    const bf16_t* kb0 = kb + (size_t)bh*SEQ*HDIM;
    const bf16_t* vt0 = vt + (size_t)bh*HDIM*SEQ;

    f32x4 acc[2][4] = {};
    float m[2][4]  = {{-1e30f,-1e30f,-1e30f,-1e30f},{-1e30f,-1e30f,-1e30f,-1e30f}};
    float ls[2][4] = {};

    bf16x8 kA[4][2], kB[4][2], vr[4][2];
    kload(kA, kb0, 0, c16, g);
    for (int kt = 0; kt < SEQ/64; kt += 2) {
        kload(kB, kb0, kt + 1, c16, g);          // prefetch next K tile
        vload(vr, vt0, kt, c16, g);              // V consumed at end of this step
        attn_step(kA, vr, aq, acc, m, ls, myP + (kt & 1)*4096, c16, g);
        kload(kA, kb0, (kt + 2 < SEQ/64) ? kt + 2 : 0, c16, g);
        vload(vr, vt0, kt + 1, c16, g);
        attn_step(kB, vr, aq, acc, m, ls, myP + ((kt + 1) & 1)*4096, c16, g);
    }

    const int b = bh >> 4, h = bh & 15;
#pragma unroll
    for (int f = 0; f < 2; ++f)
#pragma unroll
        for (int i = 0; i < 4; ++i) {
            float inv = 1.0f / ls[f][i];
            long srow = q0 + f*16 + g*4 + i;
#pragma unroll
            for (int nf = 0; nf < 4; ++nf)
                ctx[((size_t)b*SEQ + srow)*DMODEL + h*HDIM + nf*16 + c16] = (bf16_t)(acc[f][nf][i]*inv);
        }
}

// ---------------- layer norm: one block per row of 1024 ----------------
__global__ __launch_bounds__(256) void ln_k(
    const float* __restrict__ a, const float* __restrict__ b,
    const float* __restrict__ g, const float* __restrict__ be,
    float* __restrict__ of, bf16_t* __restrict__ ob)
{
    const long row = blockIdx.x;
    const int tid = threadIdx.x;
    float4 v = ((const float4*)(a + row*DMODEL))[tid];
    if (b) {
        float4 u = ((const float4*)(b + row*DMODEL))[tid];
        v.x += u.x; v.y += u.y; v.z += u.z; v.w += u.w;
    }
    float s = v.x + v.y + v.z + v.w;
    float q = v.x*v.x + v.y*v.y + v.z*v.z + v.w*v.w;
#pragma unroll
    for (int msk = 1; msk < 64; msk <<= 1) {
        s += __shfl_xor(s, msk, 64);
        q += __shfl_xor(q, msk, 64);
    }
    __shared__ float sb[4], qb2[4];
    int w = tid >> 6, lid = tid & 63;
    if (lid == 0) { sb[w] = s; qb2[w] = q; }
    __syncthreads();
    s = sb[0] + sb[1] + sb[2] + sb[3];
    q = qb2[0] + qb2[1] + qb2[2] + qb2[3];
    float mean = s * (1.f/1024.f);
    float var  = q * (1.f/1024.f) - mean*mean;
    float rs   = rsqrtf(var + 1e-5f);
    float4 gv = ((const float4*)g)[tid];
    float4 bv = ((const float4*)be)[tid];
    float o0 = (v.x-mean)*rs*gv.x + bv.x;
    float o1 = (v.y-mean)*rs*gv.y + bv.y;
    float o2 = (v.z-mean)*rs*gv.z + bv.z;
    float o3 = (v.w-mean)*rs*gv.w + bv.w;
    if (ob) {
        bf16x4 o; o[0]=(bf16_t)o0; o[1]=(bf16_t)o1; o[2]=(bf16_t)o2; o[3]=(bf16_t)o3;
        *(bf16x4*)(ob + row*DMODEL + tid*4) = o;
    } else {
        float4 o = make_float4(o0, o1, o2, o3);
        ((float4*)(of + row*DMODEL))[tid] = o;
    }
}

// ---------------- host ----------------
extern "C" void kernel_launch(void* const* d_in, const int* in_sizes, int n_in,
                              void* d_out, int out_size, void* d_ws, size_t ws_size,
                              hipStream_t stream)
{
    const float* x   = (const float*)d_in[0];
    const float* Wq  = (const float*)d_in[1];
    const float* bq  = (const float*)d_in[2];
    const float* Wk  = (const float*)d_in[3];
    const float* bk  = (const float*)d_in[4];
    const float* Wv  = (const float*)d_in[5];
    const float* bvv = (const float*)d_in[6];
    const float* Wo  = (const float*)d_in[7];
    const float* bo  = (const float*)d_in[8];
    const float* W1  = (const float*)d_in[9];
    const float* b1  = (const float*)d_in[10];
    const float* W2  = (const float*)d_in[11];
    const float* b2  = (const float*)d_in[12];
    const float* g1  = (const float*)d_in[13];
    const float* be1 = (const float*)d_in[14];
    const float* g2  = (const float*)d_in[15];
    const float* be2 = (const float*)d_in[16];

    char* ws = (char*)d_ws;
    bf16_t* xb   = (bf16_t*)(ws + XB_OFF);
    bf16_t* qbuf = (bf16_t*)(ws + Q_OFF);
    bf16_t* kbuf = (bf16_t*)(ws + K_OFF);
    bf16_t* vtb  = (bf16_t*)(ws + VT_OFF);
    bf16_t* ffn1 = (bf16_t*)(ws + FFN1_OFF);
    bf16_t* ctxb = (bf16_t*)(ws + CTX_OFF);
    float*  out1 = (float*)(ws + OUT1_OFF);
    bf16_t* ln1b = (bf16_t*)(ws + LN1_OFF);
    bf16_t* wqb  = (bf16_t*)(ws + WQ_OFF);
    bf16_t* wkb  = (bf16_t*)(ws + WK_OFF);
    bf16_t* wvb  = (bf16_t*)(ws + WV_OFF);
    bf16_t* wob  = (bf16_t*)(ws + WO_OFF);
    bf16_t* w1b  = (bf16_t*)(ws + W1_OFF);
    bf16_t* w2b  = (bf16_t*)(ws + W2_OFF);
    float*  dout = (float*)d_out;

    auto cast = [&](const float* s, bf16_t* d, long n) {
        int n8 = (int)(n / 8);
        cast_bf16_k<<<(n8 + 255)/256, 256, 0, stream>>>(s, d, n8);
    };
    cast(x,  xb,  (long)MTOK*DMODEL);
    cast(Wq, wqb, (long)DMODEL*DMODEL);
    cast(Wk, wkb, (long)DMODEL*DMODEL);
    cast(Wv, wvb, (long)DMODEL*DMODEL);
    cast(Wo, wob, (long)DMODEL*DMODEL);
    cast(W1, w1b, (long)DFF*DMODEL);
    cast(W2, w2b, (long)DMODEL*DFF);

    dim3 blk(256);
    // QKV projections (Q pre-scaled by 1/sqrt(hd) = 0.125)
    gemm_bt<0><<<dim3(DMODEL/128, MTOK/128), blk, 0, stream>>>(xb, wqb, bq, qbuf, nullptr, MTOK, DMODEL, DMODEL, 0.125f);
    gemm_bt<0><<<dim3(DMODEL/128, MTOK/128), blk, 0, stream>>>(xb, wkb, bk, kbuf, nullptr, MTOK, DMODEL, DMODEL, 1.f);
    gemm_bt<1><<<dim3(DMODEL/128, MTOK/128), blk, 0, stream>>>(xb, wvb, bvv, vtb, nullptr, MTOK, DMODEL, DMODEL, 1.f);
    // attention
    attn_k<<<dim3(SEQ/128, 4*NHEAD), blk, 0, stream>>>(qbuf, kbuf, vtb, ctxb);
    // Wo projection -> out1 (fp32)
    gemm_bt<2><<<dim3(DMODEL/128, MTOK/128), blk, 0, stream>>>(ctxb, wob, bo, out1, nullptr, MTOK, DMODEL, DMODEL, 1.f);
    // LN1: ln1 = LN(x + out1) -> bf16
    ln_k<<<MTOK, blk, 0, stream>>>(x, out1, g1, be1, nullptr, ln1b);
    // FFN1: relu(ln1 @ W1^T + b1) -> bf16
    gemm_bt<3><<<dim3(DFF/128, MTOK/128), blk, 0, stream>>>(ln1b, w1b, b1, ffn1, nullptr, MTOK, DFF, DMODEL, 1.f);
    // FFN2: s2 = out1 + (ffn1 @ W2^T + b2) -> fp32, in place over out1
    gemm_bt<4><<<dim3(DMODEL/128, MTOK/128), blk, 0, stream>>>(ffn1, w2b, b2, out1, out1, MTOK, DMODEL, DFF, 1.f);
    // LN2 -> d_out (fp32)
    ln_k<<<MTOK, blk, 0, stream>>>(out1, nullptr, g2, be2, dout, nullptr);
}

// Round 4
// 585.815 us; speedup vs baseline: 1.4632x; 1.0027x over previous
//
#include <hip/hip_runtime.h>

typedef __bf16 bf16_t;
typedef __bf16 bf16x8 __attribute__((ext_vector_type(8)));
typedef __bf16 bf16x4 __attribute__((ext_vector_type(4)));
typedef float  f32x4  __attribute__((ext_vector_type(4)));

#define SEQ   2048
#define DMODEL 1024
#define DFF   4096
#define NHEAD 16
#define HDIM  64
#define MTOK  8192   // 4 * 2048

// ---------------- workspace layout (bytes) ----------------
#define MB (size_t)(1024*1024)
static const size_t XB_OFF   = 0;          // bf16 [8192][1024]  (aliased by FFN1 later)
static const size_t Q_OFF    = 16*MB;      // bf16 [B,H,S,64]
static const size_t K_OFF    = 32*MB;      // bf16 [B,H,S,64]
static const size_t VT_OFF   = 48*MB;      // bf16 [B,H,64,S]
static const size_t FFN1_OFF = 0;          // bf16 [8192][4096] aliases XB..VT (all dead then)
static const size_t CTX_OFF  = 64*MB;      // bf16 [8192][1024]
static const size_t OUT1_OFF = 80*MB;      // f32  [8192][1024]; later s2 = out1+out2 in place
static const size_t LN1_OFF  = 112*MB;     // bf16 [8192][1024]
static const size_t WQ_OFF   = 128*MB;
static const size_t WK_OFF   = 130*MB;
static const size_t WV_OFF   = 132*MB;
static const size_t WO_OFF   = 134*MB;
static const size_t W1_OFF   = 136*MB;     // bf16 [4096][1024]
static const size_t W2_OFF   = 144*MB;     // bf16 [1024][4096]  (ends at 152MB)

// ---------------- helpers ----------------
__device__ inline void gload16(const void* g, void* l) {
    __builtin_amdgcn_global_load_lds((__attribute__((address_space(1))) void*)g,
                                     (__attribute__((address_space(3))) void*)l, 16, 0, 0);
}

__global__ __launch_bounds__(256) void cast_bf16_k(const float* __restrict__ s,
                                                   bf16_t* __restrict__ d, int n8) {
    int i = blockIdx.x * 256 + threadIdx.x;
    if (i >= n8) return;
    float4 v0 = ((const float4*)s)[2*i];
    float4 v1 = ((const float4*)s)[2*i+1];
    bf16x8 o;
    o[0]=(bf16_t)v0.x; o[1]=(bf16_t)v0.y; o[2]=(bf16_t)v0.z; o[3]=(bf16_t)v0.w;
    o[4]=(bf16_t)v1.x; o[5]=(bf16_t)v1.y; o[6]=(bf16_t)v1.z; o[7]=(bf16_t)v1.w;
    *(bf16x8*)(d + (size_t)i*8) = o;
}

// ---------------- GEMM: C = (A(MxK) * B(NxK)^T + bias) * scale, epilogue variants ----------------
// EPI 0: Q/K scatter -> bf16 [B,H,S,64]   (scale folds the 1/sqrt(hd) into Q)
// EPI 1: V scatter transposed -> bf16 [B,H,64,S]
// EPI 2: fp32 + bias -> out (out1)
// EPI 3: relu -> bf16 (ffn1)
// EPI 4: fp32 + bias + aux[r,c] -> out (s2 = out1+out2, may alias aux)
template<int EPI>
__global__ __launch_bounds__(256, 2) void gemm_bt(
    const bf16_t* __restrict__ A, const bf16_t* __restrict__ Bm,
    const float* __restrict__ bias, void* __restrict__ out,
    const float* __restrict__ aux, int M, int N, int K, float scale)
{
    __shared__ bf16_t As[128*64];
    __shared__ bf16_t Bs[128*64];
    const int tid = threadIdx.x;
    const int l   = tid & 63;
    const int wid = tid >> 6;
    const int wm  = wid >> 1, wn = wid & 1;
    const int c16 = l & 15,   g  = l >> 4;
    const long brow = (long)blockIdx.y * 128;
    const long bcol = (long)blockIdx.x * 128;

    f32x4 acc[4][4] = {};

    const int nkt = K >> 6;
    for (int kt = 0; kt < nkt; ++kt) {
        __syncthreads();   // protect LDS while other waves may still be reading
        const bf16_t* Ag = A  + brow * K + kt*64;
        const bf16_t* Bg = Bm + bcol * K + kt*64;
#pragma unroll
        for (int c = 0; c < 4; ++c) {
            int e   = (c*256 + tid) * 8;     // flat bf16 element in 128x64 tile
            int row = e >> 6;
            int col = e & 63;
            gload16(Ag + (long)row*K + col, &As[e]);
            gload16(Bg + (long)row*K + col, &Bs[e]);
        }
        __syncthreads();   // drains vmcnt(0): LDS tiles ready
#pragma unroll
        for (int kk = 0; kk < 2; ++kk) {
            bf16x8 af[4], bfr[4];
#pragma unroll
            for (int mi = 0; mi < 4; ++mi)
                af[mi] = *(const bf16x8*)&As[(wm*64 + mi*16 + c16)*64 + kk*32 + 8*g];
#pragma unroll
            for (int ni = 0; ni < 4; ++ni)
                bfr[ni] = *(const bf16x8*)&Bs[(wn*64 + ni*16 + c16)*64 + kk*32 + 8*g];
#pragma unroll
            for (int mi = 0; mi < 4; ++mi)
#pragma unroll
                for (int ni = 0; ni < 4; ++ni)
                    acc[mi][ni] = __builtin_amdgcn_mfma_f32_16x16x32_bf16(
                        af[mi], bfr[ni], acc[mi][ni], 0, 0, 0);
        }
    }

    // epilogue: lane l, reg i -> row = ...+ g*4 + i, col = ...+ c16
#pragma unroll
    for (int ni = 0; ni < 4; ++ni) {
        const long c = bcol + wn*64 + ni*16 + c16;
        const float bv = bias[c];
#pragma unroll
        for (int mi = 0; mi < 4; ++mi) {
#pragma unroll
            for (int i = 0; i < 4; ++i) {
                const long r = brow + wm*64 + mi*16 + g*4 + i;
                float v = (acc[mi][ni][i] + bv) * scale;
                if constexpr (EPI == 0) {
                    long off = (((r >> 11)*NHEAD + (c >> 6))*SEQ + (r & (SEQ-1)))*HDIM + (c & 63);
                    ((bf16_t*)out)[off] = (bf16_t)v;
                } else if constexpr (EPI == 1) {
                    long off = (((r >> 11)*NHEAD + (c >> 6))*HDIM + (c & 63))*SEQ + (r & (SEQ-1));
                    ((bf16_t*)out)[off] = (bf16_t)v;
                } else if constexpr (EPI == 2) {
                    ((float*)out)[r*N + c] = v;
                } else if constexpr (EPI == 3) {
                    ((bf16_t*)out)[r*N + c] = (bf16_t)fmaxf(v, 0.f);
                } else {
                    ((float*)out)[r*N + c] = v + aux[r*N + c];
                }
            }
        }
    }
}

// ---------------- flash attention, swapped-QK + defer-max + register pipeline ----------------
// grid: (S/128, B*H). 4 independent waves/block, 32 q-rows per wave.
// QK^T computed SWAPPED: mfma(K, Q) -> C[col = q = c16][row = key = 16jk+4g+i].
// Softmax stats (m, ls) are lane-local per q = c16: local 16-max tree + 2 shfls.
// defer-max (THR=8): rescale branch skipped when tile max doesn't grow.
// K double-buffered in registers; V issued at top, consumed at end.
// P goes through parity-double-buffered XOR-swizzled LDS (conflict-free, verified R2).
__device__ __forceinline__ void kload(bf16x8 (&dst)[4][2], const bf16_t* kb0,
                                      int ktt, int c16, int g) {
    const bf16_t* kbase = kb0 + (size_t)ktt*64*HDIM;
#pragma unroll
    for (int jk = 0; jk < 4; ++jk)
#pragma unroll
        for (int ks = 0; ks < 2; ++ks)
            dst[jk][ks] = *(const bf16x8*)(kbase + (size_t)(16*jk + c16)*HDIM + ks*32 + 8*g);
}

__device__ __forceinline__ void vload(bf16x8 (&vr)[4][2], const bf16_t* vt0,
                                      int ktt, int c16, int g) {
#pragma unroll
    for (int nf = 0; nf < 4; ++nf)
#pragma unroll
        for (int ks = 0; ks < 2; ++ks)
            vr[nf][ks] = *(const bf16x8*)(vt0 + (size_t)(16*nf + c16)*SEQ + ktt*64 + ks*32 + 8*g);
}

__device__ __forceinline__ void attn_step(
    const bf16x8 (&kr)[4][2], const bf16x8 (&vr)[4][2], const bf16x8 (&aq)[2][2],
    f32x4 (&acc)[2][4], float (&m)[2], float (&ls)[2],
    char* myP, int c16, int g)
{
    // ---- QK^T swapped: s[qf][jk][i] = S[key = 16jk+4g+i][q = qf*16 + c16] ----
    f32x4 s[2][4];
    const f32x4 z = {0.f, 0.f, 0.f, 0.f};
    __builtin_amdgcn_s_setprio(1);
#pragma unroll
    for (int qf = 0; qf < 2; ++qf)
#pragma unroll
        for (int jk = 0; jk < 4; ++jk) {
            s[qf][jk] = __builtin_amdgcn_mfma_f32_16x16x32_bf16(kr[jk][0], aq[qf][0], z, 0, 0, 0);
            s[qf][jk] = __builtin_amdgcn_mfma_f32_16x16x32_bf16(kr[jk][1], aq[qf][1], s[qf][jk], 0, 0, 0);
        }
    __builtin_amdgcn_s_setprio(0);
    // ---- online softmax, per-lane q = c16 ----
#pragma unroll
    for (int qf = 0; qf < 2; ++qf) {
        float a0 = fmaxf(fmaxf(s[qf][0][0], s[qf][0][1]), fmaxf(s[qf][0][2], s[qf][0][3]));
        float a1 = fmaxf(fmaxf(s[qf][1][0], s[qf][1][1]), fmaxf(s[qf][1][2], s[qf][1][3]));
        float a2 = fmaxf(fmaxf(s[qf][2][0], s[qf][2][1]), fmaxf(s[qf][2][2], s[qf][2][3]));
        float a3 = fmaxf(fmaxf(s[qf][3][0], s[qf][3][1]), fmaxf(s[qf][3][2], s[qf][3][3]));
        float pm = fmaxf(fmaxf(a0, a1), fmaxf(a2, a3));
        pm = fmaxf(pm, __shfl_xor(pm, 16, 64));
        pm = fmaxf(pm, __shfl_xor(pm, 32, 64));
        if (__any(pm > m[qf] + 8.0f)) {          // defer-max: rare after tile 0
            float mn   = fmaxf(m[qf], pm);
            float corr = __expf(m[qf] - mn);
            ls[qf] *= corr;
            m[qf]   = mn;
            // redistribute corr from q=c16 lanes to q=4g+i addressing
            float c0 = __shfl(corr, 4*g + 0, 64);
            float c1 = __shfl(corr, 4*g + 1, 64);
            float c2 = __shfl(corr, 4*g + 2, 64);
            float c3 = __shfl(corr, 4*g + 3, 64);
#pragma unroll
            for (int nf = 0; nf < 4; ++nf) {
                acc[qf][nf][0] *= c0; acc[qf][nf][1] *= c1;
                acc[qf][nf][2] *= c2; acc[qf][nf][3] *= c3;
            }
        }
        float rsum = 0.f;
#pragma unroll
        for (int jk = 0; jk < 4; ++jk)
#pragma unroll
            for (int i = 0; i < 4; ++i) {
                s[qf][jk][i] = __expf(s[qf][jk][i] - m[qf]);
                rsum += s[qf][jk][i];
            }
        rsum += __shfl_xor(rsum, 16, 64);
        rsum += __shfl_xor(rsum, 32, 64);
        ls[qf] += rsum;
    }
    // ---- P -> LDS: row = q = qf*16+c16, key cols 16jk+4g..+3, swizzled ----
#pragma unroll
    for (int qf = 0; qf < 2; ++qf)
#pragma unroll
        for (int jk = 0; jk < 4; ++jk) {
            bf16x4 pk;
            pk[0]=(bf16_t)s[qf][jk][0]; pk[1]=(bf16_t)s[qf][jk][1];
            pk[2]=(bf16_t)s[qf][jk][2]; pk[3]=(bf16_t)s[qf][jk][3];
            *(bf16x4*)(myP + (qf*16 + c16)*128 + ((32*jk + 8*g) ^ ((c16 & 7) << 4))) = pk;
        }
    asm volatile("s_waitcnt lgkmcnt(0)" ::: "memory");  // P writes visible (lgkm only; vm loads stay in flight)
    __builtin_amdgcn_sched_barrier(0);
    // ---- PV: A = P[row = q = qf*16+c16][keys ks*32+8g..], B = V^T rows d = 16nf+c16 ----
    __builtin_amdgcn_s_setprio(1);
#pragma unroll
    for (int qf = 0; qf < 2; ++qf)
#pragma unroll
        for (int ks = 0; ks < 2; ++ks) {
            bf16x8 pa = *(const bf16x8*)(myP + (qf*16 + c16)*128 + ((ks*64 + 16*g) ^ ((c16 & 7) << 4)));
#pragma unroll
            for (int nf = 0; nf < 4; ++nf)
                acc[qf][nf] = __builtin_amdgcn_mfma_f32_16x16x32_bf16(pa, vr[nf][ks], acc[qf][nf], 0, 0, 0);
        }
    __builtin_amdgcn_s_setprio(0);
    asm volatile("" ::: "memory");  // pin P reads before next iteration's writes
}

__global__ __launch_bounds__(256, 2) void attn_k(
    const bf16_t* __restrict__ qb, const bf16_t* __restrict__ kb,
    const bf16_t* __restrict__ vt, bf16_t* __restrict__ ctx)
{
    const int bh = blockIdx.y;
    const int w  = threadIdx.x >> 6;
    const int l  = threadIdx.x & 63;
    const int c16 = l & 15, g = l >> 4;
    const int q0 = blockIdx.x*128 + w*32;

    __shared__ char Ps[4*8192];
    char* myP = &Ps[w*8192];

    // Q fragments (B-operand of swapped QK): B[col=q=c16][k=8g..] — same load as before
    bf16x8 aq[2][2];
#pragma unroll
    for (int qf = 0; qf < 2; ++qf) {
        const bf16_t* qrow = qb + ((size_t)bh*SEQ + q0 + qf*16 + c16)*HDIM;
        aq[qf][0] = *(const bf16x8*)(qrow + 8*g);
        aq[qf][1] = *(const bf16x8*)(qrow + 32 + 8*g);
    }

    const bf16_t* kb0 = kb + (size_t)bh*SEQ*HDIM;
    const bf16_t* vt0 = vt + (size_t)bh*HDIM*SEQ;

    f32x4 acc[2][4] = {};
    float m[2]  = {-1e30f, -1e30f};
    float ls[2] = {0.f, 0.f};

    bf16x8 kA[4][2], kB[4][2], vr[4][2];
    kload(kA, kb0, 0, c16, g);
    for (int kt = 0; kt < SEQ/64; kt += 2) {
        kload(kB, kb0, kt + 1, c16, g);          // prefetch next K tile
        vload(vr, vt0, kt, c16, g);              // V consumed at end of this step
        attn_step(kA, vr, aq, acc, m, ls, myP + (kt & 1)*4096, c16, g);
        kload(kA, kb0, (kt + 2 < SEQ/64) ? kt + 2 : 0, c16, g);
        vload(vr, vt0, kt + 1, c16, g);
        attn_step(kB, vr, aq, acc, m, ls, myP + ((kt + 1) & 1)*4096, c16, g);
    }

    const int b = bh >> 4, h = bh & 15;
#pragma unroll
    for (int qf = 0; qf < 2; ++qf) {
        // redistribute ls from q=c16 lanes to q=4g+i addressing (once per kernel)
        float i0 = 1.0f / __shfl(ls[qf], 4*g + 0, 64);
        float i1 = 1.0f / __shfl(ls[qf], 4*g + 1, 64);
        float i2 = 1.0f / __shfl(ls[qf], 4*g + 2, 64);
        float i3 = 1.0f / __shfl(ls[qf], 4*g + 3, 64);
#pragma unroll
        for (int nf = 0; nf < 4; ++nf) {
            long col = (size_t)h*HDIM + nf*16 + c16;
            long rb  = (size_t)b*SEQ + q0 + qf*16 + 4*g;
            ctx[(rb + 0)*DMODEL + col] = (bf16_t)(acc[qf][nf][0] * i0);
            ctx[(rb + 1)*DMODEL + col] = (bf16_t)(acc[qf][nf][1] * i1);
            ctx[(rb + 2)*DMODEL + col] = (bf16_t)(acc[qf][nf][2] * i2);
            ctx[(rb + 3)*DMODEL + col] = (bf16_t)(acc[qf][nf][3] * i3);
        }
    }
}

// ---------------- layer norm: one block per row of 1024 ----------------
__global__ __launch_bounds__(256) void ln_k(
    const float* __restrict__ a, const float* __restrict__ b,
    const float* __restrict__ g, const float* __restrict__ be,
    float* __restrict__ of, bf16_t* __restrict__ ob)
{
    const long row = blockIdx.x;
    const int tid = threadIdx.x;
    float4 v = ((const float4*)(a + row*DMODEL))[tid];
    if (b) {
        float4 u = ((const float4*)(b + row*DMODEL))[tid];
        v.x += u.x; v.y += u.y; v.z += u.z; v.w += u.w;
    }
    float s = v.x + v.y + v.z + v.w;
    float q = v.x*v.x + v.y*v.y + v.z*v.z + v.w*v.w;
#pragma unroll
    for (int msk = 1; msk < 64; msk <<= 1) {
        s += __shfl_xor(s, msk, 64);
        q += __shfl_xor(q, msk, 64);
    }
    __shared__ float sb[4], qb2[4];
    int w = tid >> 6, lid = tid & 63;
    if (lid == 0) { sb[w] = s; qb2[w] = q; }
    __syncthreads();
    s = sb[0] + sb[1] + sb[2] + sb[3];
    q = qb2[0] + qb2[1] + qb2[2] + qb2[3];
    float mean = s * (1.f/1024.f);
    float var  = q * (1.f/1024.f) - mean*mean;
    float rs   = rsqrtf(var + 1e-5f);
    float4 gv = ((const float4*)g)[tid];
    float4 bv = ((const float4*)be)[tid];
    float o0 = (v.x-mean)*rs*gv.x + bv.x;
    float o1 = (v.y-mean)*rs*gv.y + bv.y;
    float o2 = (v.z-mean)*rs*gv.z + bv.z;
    float o3 = (v.w-mean)*rs*gv.w + bv.w;
    if (ob) {
        bf16x4 o; o[0]=(bf16_t)o0; o[1]=(bf16_t)o1; o[2]=(bf16_t)o2; o[3]=(bf16_t)o3;
        *(bf16x4*)(ob + row*DMODEL + tid*4) = o;
    } else {
        float4 o = make_float4(o0, o1, o2, o3);
        ((float4*)(of + row*DMODEL))[tid] = o;
    }
}

// ---------------- host ----------------
extern "C" void kernel_launch(void* const* d_in, const int* in_sizes, int n_in,
                              void* d_out, int out_size, void* d_ws, size_t ws_size,
                              hipStream_t stream)
{
    const float* x   = (const float*)d_in[0];
    const float* Wq  = (const float*)d_in[1];
    const float* bq  = (const float*)d_in[2];
    const float* Wk  = (const float*)d_in[3];
    const float* bk  = (const float*)d_in[4];
    const float* Wv  = (const float*)d_in[5];
    const float* bvv = (const float*)d_in[6];
    const float* Wo  = (const float*)d_in[7];
    const float* bo  = (const float*)d_in[8];
    const float* W1  = (const float*)d_in[9];
    const float* b1  = (const float*)d_in[10];
    const float* W2  = (const float*)d_in[11];
    const float* b2  = (const float*)d_in[12];
    const float* g1  = (const float*)d_in[13];
    const float* be1 = (const float*)d_in[14];
    const float* g2  = (const float*)d_in[15];
    const float* be2 = (const float*)d_in[16];

    char* ws = (char*)d_ws;
    bf16_t* xb   = (bf16_t*)(ws + XB_OFF);
    bf16_t* qbuf = (bf16_t*)(ws + Q_OFF);
    bf16_t* kbuf = (bf16_t*)(ws + K_OFF);
    bf16_t* vtb  = (bf16_t*)(ws + VT_OFF);
    bf16_t* ffn1 = (bf16_t*)(ws + FFN1_OFF);
    bf16_t* ctxb = (bf16_t*)(ws + CTX_OFF);
    float*  out1 = (float*)(ws + OUT1_OFF);
    bf16_t* ln1b = (bf16_t*)(ws + LN1_OFF);
    bf16_t* wqb  = (bf16_t*)(ws + WQ_OFF);
    bf16_t* wkb  = (bf16_t*)(ws + WK_OFF);
    bf16_t* wvb  = (bf16_t*)(ws + WV_OFF);
    bf16_t* wob  = (bf16_t*)(ws + WO_OFF);
    bf16_t* w1b  = (bf16_t*)(ws + W1_OFF);
    bf16_t* w2b  = (bf16_t*)(ws + W2_OFF);
    float*  dout = (float*)d_out;

    auto cast = [&](const float* s, bf16_t* d, long n) {
        int n8 = (int)(n / 8);
        cast_bf16_k<<<(n8 + 255)/256, 256, 0, stream>>>(s, d, n8);
    };
    cast(x,  xb,  (long)MTOK*DMODEL);
    cast(Wq, wqb, (long)DMODEL*DMODEL);
    cast(Wk, wkb, (long)DMODEL*DMODEL);
    cast(Wv, wvb, (long)DMODEL*DMODEL);
    cast(Wo, wob, (long)DMODEL*DMODEL);
    cast(W1, w1b, (long)DFF*DMODEL);
    cast(W2, w2b, (long)DMODEL*DFF);

    dim3 blk(256);
    // QKV projections (Q pre-scaled by 1/sqrt(hd) = 0.125)
    gemm_bt<0><<<dim3(DMODEL/128, MTOK/128), blk, 0, stream>>>(xb, wqb, bq, qbuf, nullptr, MTOK, DMODEL, DMODEL, 0.125f);
    gemm_bt<0><<<dim3(DMODEL/128, MTOK/128), blk, 0, stream>>>(xb, wkb, bk, kbuf, nullptr, MTOK, DMODEL, DMODEL, 1.f);
    gemm_bt<1><<<dim3(DMODEL/128, MTOK/128), blk, 0, stream>>>(xb, wvb, bvv, vtb, nullptr, MTOK, DMODEL, DMODEL, 1.f);
    // attention
    attn_k<<<dim3(SEQ/128, 4*NHEAD), blk, 0, stream>>>(qbuf, kbuf, vtb, ctxb);
    // Wo projection -> out1 (fp32)
    gemm_bt<2><<<dim3(DMODEL/128, MTOK/128), blk, 0, stream>>>(ctxb, wob, bo, out1, nullptr, MTOK, DMODEL, DMODEL, 1.f);
    // LN1: ln1 = LN(x + out1) -> bf16
    ln_k<<<MTOK, blk, 0, stream>>>(x, out1, g1, be1, nullptr, ln1b);
    // FFN1: relu(ln1 @ W1^T + b1) -> bf16
    gemm_bt<3><<<dim3(DFF/128, MTOK/128), blk, 0, stream>>>(ln1b, w1b, b1, ffn1, nullptr, MTOK, DFF, DMODEL, 1.f);
    // FFN2: s2 = out1 + (ffn1 @ W2^T + b2) -> fp32, in place over out1
    gemm_bt<4><<<dim3(DMODEL/128, MTOK/128), blk, 0, stream>>>(ffn1, w2b, b2, out1, out1, MTOK, DMODEL, DFF, 1.f);
    // LN2 -> d_out (fp32)
    ln_k<<<MTOK, blk, 0, stream>>>(out1, nullptr, g2, be2, dout, nullptr);
}